// Round 5
// baseline (70.846 us; speedup 1.0000x reference)
//
#include <hip/hip_runtime.h>
#include <hip/hip_bf16.h>

// Problem constants (from reference setup_inputs)
#define B_N    4096      // batch
#define D_K    1024      // feature dim
#define MARGIN 0.3f
#define BIGM   1e5f

typedef __attribute__((ext_vector_type(8))) short short8;
typedef __attribute__((ext_vector_type(4))) float f32x4;

__device__ inline ushort f2bf(float f) {
    unsigned u = __float_as_uint(f);
    unsigned r = (u + 0x7fffu + ((u >> 16) & 1u)) >> 16;
    return (ushort)r;
}

__device__ inline void async16(const ushort* g, ushort* l) {
    __builtin_amdgcn_global_load_lds(
        (const __attribute__((address_space(1))) void*)g,
        (__attribute__((address_space(3))) void*)l,
        16, 0, 0);
}

// Fused prep: convert feat -> bf16 (blocks 0..4095) and lut[id] -> bf16
// (blocks 4096..8191), compute fp32 squared row norms, and init min/max bufs.
__global__ void prep_all(const float* __restrict__ feat,
                         const float* __restrict__ lut,
                         const int* __restrict__ id,
                         ushort* __restrict__ featB, ushort* __restrict__ oimB,
                         float* __restrict__ sq_a, float* __restrict__ sq_b,
                         int* __restrict__ maxb, int* __restrict__ minb) {
    int b = blockIdx.x;
    int t = threadIdx.x;                       // 256 threads, 4 floats each
    if (b < 16) {                              // 16*256 = 4096 entries
        int i = b * 256 + t;
        maxb[i] = 0;                           // 0.0f
        minb[i] = 0x7F800000;                  // +inf
    }
    const float* src; ushort* dst; float* sq;
    if (b < B_N) {
        src = feat + (size_t)b * D_K;
        dst = featB + (size_t)b * D_K;
        sq  = sq_a + b;
    } else {
        int row = b - B_N;
        src = lut + (size_t)id[row] * D_K;
        dst = oimB + (size_t)row * D_K;
        sq  = sq_b + row;
    }
    float4 v = ((const float4*)src)[t];
    float ss = v.x * v.x + v.y * v.y + v.z * v.z + v.w * v.w;
    ushort4 bb;
    bb.x = f2bf(v.x); bb.y = f2bf(v.y); bb.z = f2bf(v.z); bb.w = f2bf(v.w);
    ((ushort4*)dst)[t] = bb;

    int lane = t & 63, w = t >> 6;
    #pragma unroll
    for (int o = 1; o < 64; o <<= 1) ss += __shfl_xor(ss, o);
    __shared__ float red[4];
    if (lane == 0) red[w] = ss;
    __syncthreads();
    if (t == 0) *sq = red[0] + red[1] + red[2] + red[3];
}

// 256x256-tile bf16 MFMA GEMM, deep-prefetch schedule:
//   - all 8 global_load_lds for tile kt+1 issued at TOP of tile kt
//     (lead = full compute body > L2/L3 latency), counted vmcnt(8),
//   - 2 barriers per K-tile (WAR fence B1, RAW fence B2), no intra-tile
//     barriers: quadrants are pure {ds_read, MFMA}, compiler-scheduled,
//   - T2 chunk-XOR swizzle (conflict-free, verified 0 last round),
//   - T1 XCD-aware block swizzle (256 blocks % 8 == 0 -> bijective),
//   - T5 setprio(1) over the compute region.
// 8 waves 2(M)x4(N); per-wave output 128x64; BK=64; LDS 128 KiB dbuf.
__global__ __launch_bounds__(512, 2)
void dist_kernel(const ushort* __restrict__ A, const ushort* __restrict__ Bm,
                 const float* __restrict__ sqa, const float* __restrict__ sqb,
                 const int* __restrict__ ids,
                 int* __restrict__ maxb, int* __restrict__ minb) {
    __shared__ ushort lA[2][256 * 64];   // 32 KB per buffer
    __shared__ ushort lB[2][256 * 64];

    const int t = threadIdx.x;
    const int lane = t & 63;
    const int wid = t >> 6;          // 8 waves
    const int wr = wid >> 2;         // 0..1 (M)
    const int wc = wid & 3;          // 0..3 (N)
    const int l15 = lane & 15;
    const int h = lane >> 4;

    // T1: XCD-aware swizzle. 256 blocks, 8 XCDs -> XCD k owns 32 contiguous
    // swz ids = row-bands {2k, 2k+1} x all 16 col-bands (A panels L2-fit).
    const int bid = blockIdx.y * gridDim.x + blockIdx.x;
    const int swz = (bid & 7) * 32 + (bid >> 3);
    const int rb = swz >> 4, cb = swz & 15;

    // ---- staging slots: 8 x (512 thr x 16B). q<4 = A tile, q>=4 = B tile.
    // LDS linear elem = (q&3)*4096 + t*8; row = elem>>6, chunk j=(elem>>3)&7.
    // Global source chunk = j ^ (row&7)  (inverse of the read swizzle).
    const ushort* gq[8];
    #pragma unroll
    for (int q = 0; q < 8; q++) {
        int elem = (q & 3) * 4096 + t * 8;
        int r = elem >> 6;
        int j = (elem >> 3) & 7;
        int col = (j ^ (r & 7)) << 3;
        gq[q] = (q < 4) ? (A  + (size_t)(rb * 256 + r) * D_K + col)
                        : (Bm + (size_t)(cb * 256 + r) * D_K + col);
    }
    const int lds_wo = wid * 512;    // wave-uniform lane-block offset (elems)

    // ---- fragment read offsets (elements), swizzled chunk per ks
    const int q7 = l15 & 7;
    const int xs0 = ((h)     ^ q7) << 3;     // ks=0 chunk
    const int xs1 = ((h + 4) ^ q7) << 3;     // ks=1 chunk
    const int arow = (wr * 128 + l15) * 64;  // + mh*4096 + mf*1024
    const int brow = (wc * 64  + l15) * 64;  // + nh*2048 + nf*1024

    f32x4 acc[8][4] = {};
    short8 af[4][2];        // current mh quadrant (reused lo->hi)
    short8 bfr[2][2][2];    // [nh][nf][ks], both held

    // ---- prologue: stage K-tile 0 into buffer 0
    #pragma unroll
    for (int q = 0; q < 8; q++) {
        ushort* dst = ((q < 4) ? &lA[0][0] : &lB[0][0]) + (q & 3) * 4096 + lds_wo;
        async16(gq[q], dst);
    }

    for (int kt = 0; kt < 16; ++kt) {
        const int s = kt & 1;
        const ushort* rA = &lA[s][0];
        const ushort* rB = &lB[s][0];
        ushort* wA = &lA[s ^ 1][0];
        ushort* wB = &lB[s ^ 1][0];
        const int nc = (kt + 1) * 64;

        // B1: WAR fence — every wave finished reading buffer s^1 (tile kt-1)
        // before anyone's tile-kt+1 DMA can land in it.
        __builtin_amdgcn_sched_barrier(0);
        __builtin_amdgcn_s_barrier();
        __builtin_amdgcn_sched_barrier(0);

        if (kt < 15) {
            // issue ALL 8 loads for tile kt+1 now; lead = full compute body
            async16(gq[0] + nc, wA + 0 * 4096 + lds_wo);
            async16(gq[1] + nc, wA + 1 * 4096 + lds_wo);
            async16(gq[2] + nc, wA + 2 * 4096 + lds_wo);
            async16(gq[3] + nc, wA + 3 * 4096 + lds_wo);
            async16(gq[4] + nc, wB + 0 * 4096 + lds_wo);
            async16(gq[5] + nc, wB + 1 * 4096 + lds_wo);
            async16(gq[6] + nc, wB + 2 * 4096 + lds_wo);
            async16(gq[7] + nc, wB + 3 * 4096 + lds_wo);
            asm volatile("s_waitcnt vmcnt(8)" ::: "memory");  // tile kt landed
        } else {
            asm volatile("s_waitcnt vmcnt(0)" ::: "memory");
        }
        __builtin_amdgcn_sched_barrier(0);
        __builtin_amdgcn_s_barrier();     // B2: RAW fence — tile kt visible
        __builtin_amdgcn_sched_barrier(0);

        __builtin_amdgcn_s_setprio(1);
        // ---- Q0: (mh0, nh0) ----
        #pragma unroll
        for (int mf = 0; mf < 4; mf++) {
            af[mf][0] = *(const short8*)(rA + arow + mf * 1024 + xs0);
            af[mf][1] = *(const short8*)(rA + arow + mf * 1024 + xs1);
        }
        #pragma unroll
        for (int nf = 0; nf < 2; nf++) {
            bfr[0][nf][0] = *(const short8*)(rB + brow + nf * 1024 + xs0);
            bfr[0][nf][1] = *(const short8*)(rB + brow + nf * 1024 + xs1);
        }
        #pragma unroll
        for (int mf = 0; mf < 4; mf++)
            #pragma unroll
            for (int nf = 0; nf < 2; nf++) {
                acc[mf][nf] = __builtin_amdgcn_mfma_f32_16x16x32_bf16(
                    af[mf][0], bfr[0][nf][0], acc[mf][nf], 0, 0, 0);
                acc[mf][nf] = __builtin_amdgcn_mfma_f32_16x16x32_bf16(
                    af[mf][1], bfr[0][nf][1], acc[mf][nf], 0, 0, 0);
            }

        // ---- Q1: (mh0, nh1) ----
        #pragma unroll
        for (int nf = 0; nf < 2; nf++) {
            bfr[1][nf][0] = *(const short8*)(rB + brow + 2048 + nf * 1024 + xs0);
            bfr[1][nf][1] = *(const short8*)(rB + brow + 2048 + nf * 1024 + xs1);
        }
        #pragma unroll
        for (int mf = 0; mf < 4; mf++)
            #pragma unroll
            for (int nf = 0; nf < 2; nf++) {
                acc[mf][2 + nf] = __builtin_amdgcn_mfma_f32_16x16x32_bf16(
                    af[mf][0], bfr[1][nf][0], acc[mf][2 + nf], 0, 0, 0);
                acc[mf][2 + nf] = __builtin_amdgcn_mfma_f32_16x16x32_bf16(
                    af[mf][1], bfr[1][nf][1], acc[mf][2 + nf], 0, 0, 0);
            }

        // ---- Q2: (mh1, nh1) ----  (af reused for high half)
        #pragma unroll
        for (int mf = 0; mf < 4; mf++) {
            af[mf][0] = *(const short8*)(rA + arow + 4096 + mf * 1024 + xs0);
            af[mf][1] = *(const short8*)(rA + arow + 4096 + mf * 1024 + xs1);
        }
        #pragma unroll
        for (int mf = 0; mf < 4; mf++)
            #pragma unroll
            for (int nf = 0; nf < 2; nf++) {
                acc[4 + mf][2 + nf] = __builtin_amdgcn_mfma_f32_16x16x32_bf16(
                    af[mf][0], bfr[1][nf][0], acc[4 + mf][2 + nf], 0, 0, 0);
                acc[4 + mf][2 + nf] = __builtin_amdgcn_mfma_f32_16x16x32_bf16(
                    af[mf][1], bfr[1][nf][1], acc[4 + mf][2 + nf], 0, 0, 0);
            }

        // ---- Q3: (mh1, nh0) ----
        #pragma unroll
        for (int mf = 0; mf < 4; mf++)
            #pragma unroll
            for (int nf = 0; nf < 2; nf++) {
                acc[4 + mf][nf] = __builtin_amdgcn_mfma_f32_16x16x32_bf16(
                    af[mf][0], bfr[0][nf][0], acc[4 + mf][nf], 0, 0, 0);
                acc[4 + mf][nf] = __builtin_amdgcn_mfma_f32_16x16x32_bf16(
                    af[mf][1], bfr[0][nf][1], acc[4 + mf][nf], 0, 0, 0);
            }
        __builtin_amdgcn_s_setprio(0);
    }

    // Epilogue: dist + masks + per-row max/min over this block's 256 cols.
    int colg[4]; float sb[4]; int idb[4];
    #pragma unroll
    for (int n = 0; n < 4; n++) {
        int c = cb * 256 + wc * 64 + n * 16 + l15;
        colg[n] = c; sb[n] = sqb[c]; idb[n] = ids[c];
    }
    #pragma unroll
    for (int m = 0; m < 8; m++) {
        #pragma unroll
        for (int r = 0; r < 4; r++) {
            int row = rb * 256 + wr * 128 + m * 16 + h * 4 + r;
            float sa = sqa[row];
            int ida = ids[row];
            float mx = 0.0f, mn = 3.0e38f;
            #pragma unroll
            for (int n = 0; n < 4; n++) {
                float s2 = sa + sb[n] - 2.0f * acc[m][n][r];
                float d = sqrtf(fmaxf(s2, 0.0f) + 1e-12f);
                bool same = (ida == idb[n]);
                float pv = (same && (row != colg[n])) ? d : 0.0f;
                float nv = same ? d + BIGM : d;
                mx = fmaxf(mx, pv);
                mn = fminf(mn, nv);
            }
            #pragma unroll
            for (int o = 1; o < 16; o <<= 1) {
                mx = fmaxf(mx, __shfl_xor(mx, o));
                mn = fminf(mn, __shfl_xor(mn, o));
            }
            if (l15 == 0) {
                atomicMax(maxb + row, __float_as_int(mx));
                atomicMin(minb + row, __float_as_int(mn));
            }
        }
    }
}

__global__ void finalize_k(const int* __restrict__ maxb, const int* __restrict__ minb,
                           float* __restrict__ out) {
    int i = blockIdx.x * blockDim.x + threadIdx.x;
    if (i < B_N) {
        float z = __int_as_float(maxb[i]) - __int_as_float(minb[i]) + MARGIN;
        out[i] = fmaxf(z, 0.0f);
    }
}

extern "C" void kernel_launch(void* const* d_in, const int* in_sizes, int n_in,
                              void* d_out, int out_size, void* d_ws, size_t ws_size,
                              hipStream_t stream) {
    const float* feat = (const float*)d_in[0];
    const float* lut  = (const float*)d_in[1];
    const int*   id   = (const int*)d_in[2];
    float* out = (float*)d_out;

    // workspace layout
    char* ws = (char*)d_ws;
    ushort* featB = (ushort*)ws;                                  // 8 MiB
    ushort* oimB  = (ushort*)(ws + (size_t)B_N * D_K * 2);        // 8 MiB
    float*  sq_a  = (float*)(ws + (size_t)2 * B_N * D_K * 2);
    float*  sq_b  = sq_a + B_N;
    int*    maxb  = (int*)(sq_b + B_N);
    int*    minb  = maxb + B_N;

    prep_all<<<2 * B_N, 256, 0, stream>>>(feat, lut, id, featB, oimB,
                                          sq_a, sq_b, maxb, minb);

    dim3 grid(B_N / 256, B_N / 256);
    dist_kernel<<<grid, 512, 0, stream>>>(featB, oimB, sq_a, sq_b, id, maxb, minb);

    finalize_k<<<(B_N + 255) / 256, 256, 0, stream>>>(maxb, minb, out);
}